// Round 1
// baseline (184.552 us; speedup 1.0000x reference)
//
#include <hip/hip_runtime.h>

// XingLoss: x_list (P=16384, N=1024, 2) f32, scale (int scalar).
// Per row p, per segment s in [0,256): uses points x[3s..3s+3] (max idx 768).
//   v1 = x[3s+1]-x[3s]; v2 = x[3s+2]-x[3s+1]; v3 = x[3s+3]-x[3s+2]
//   direct = cross(v1,v2) >= 0
//   sina   = cross(v1,v3) / (|v1||v3|)
//   term   = direct ? relu(-sina) : relu(sina)
// out = scale * sum(term) / (segn * P)
//
// R2 -> R3 analysis: top-5 rocprof dispatches are ALL 512MiB fillBuffer
// (~78us each) = harness ws re-poison inside the timed region; our kernels
// are < 77us each, so partial+reduce ~= 182 - 2*78 ~= 26us vs a 100.9MB
// read floor of ~16us. Changes:
//   * 2048 blocks x 8 contiguous rows (exactly 8 blocks/CU resident),
//     per-thread accumulation across rows -> 8x fewer block reductions
//     and 8x fewer partials.
//   * global_load_lds width=16 direct-to-LDS staging (no VGPR roundtrip),
//     double-buffered: issue row r+1 right after the barrier, compute row
//     r while loads fly; barrier vmcnt drain is the handoff.
//   * reduce kernel reads 8KB (2048 partials) instead of 64KB.

#define N_PTS     1024
#define SEGN      (N_PTS / 4)        // 256 segments per row
#define BLOCK     256                // thread s -> segment s
#define ROWS      8                  // rows per block; grid = P/ROWS = 2048
#define ROW_F4    385                // 16B chunks of used prefix (1540 floats)
#define ROW_FLT   (ROW_F4 * 4)       // 1540 floats = 6160 B per buffer

#define GLOAD_LDS16(g, l)                                                  \
    __builtin_amdgcn_global_load_lds(                                      \
        (const __attribute__((address_space(1))) unsigned int*)(g),        \
        (__attribute__((address_space(3))) unsigned int*)(l), 16, 0, 0)

__device__ __forceinline__ void stage_row(const float* __restrict__ rowsrc,
                                          float* lbuf, int t)
{
    // Linear layout: chunk i -> lbuf floats [4i, 4i+4). Matches the
    // wave-uniform-base + lane*16 LDS write rule of global_load_lds.
    GLOAD_LDS16(rowsrc + 4 * t, lbuf + 4 * t);
    if (t < ROW_F4 - BLOCK)
        GLOAD_LDS16(rowsrc + 4 * (BLOCK + t), lbuf + 4 * (BLOCK + t));
}

__global__ __launch_bounds__(BLOCK, 8)
void xing_partial_kernel(const float* __restrict__ x,
                         float*       __restrict__ partial)
{
    const int t = threadIdx.x;
    const int b = blockIdx.x;

    __shared__ float rowf[2][ROW_FLT];   // 2 x 6160 B; 8 blocks/CU -> 98.6 KB

    const size_t row0 = (size_t)b * ROWS;
    stage_row(x + row0 * (N_PTS * 2), rowf[0], t);

    float acc = 0.0f;

    #pragma unroll
    for (int r = 0; r < ROWS; ++r) {
        // Barrier drains vmcnt -> rowf[r&1] is fully staged; also
        // guarantees everyone finished reading rowf[(r)&1^1] last iter.
        __syncthreads();

        if (r + 1 < ROWS)
            stage_row(x + (row0 + r + 1) * (size_t)(N_PTS * 2),
                      rowf[(r + 1) & 1], t);   // flies during compute below

        const float2* pts = reinterpret_cast<const float2*>(rowf[r & 1]);
        const float2 a = pts[3 * t + 0];
        const float2 bb = pts[3 * t + 1];
        const float2 c = pts[3 * t + 2];
        const float2 d = pts[3 * t + 3];

        const float v1x = bb.x - a.x,  v1y = bb.y - a.y;
        const float v2x = c.x - bb.x,  v2y = c.y - bb.y;
        const float v3x = d.x - c.x,   v3y = d.y - c.y;

        const float cross12 = v1x * v2y - v1y * v2x;
        const float cross13 = v1x * v3y - v1y * v3x;

        const float n1 = v1x * v1x + v1y * v1y;
        const float n3 = v3x * v3x + v3y * v3y;
        const float sina = cross13 * rsqrtf(n1 * n3);

        acc += (cross12 >= 0.0f) ? fmaxf(-sina, 0.0f) : fmaxf(sina, 0.0f);
    }

    // Block reduction: wave-64 shuffle, then 4 partial sums via LDS.
    #pragma unroll
    for (int off = 32; off > 0; off >>= 1)
        acc += __shfl_down(acc, off, 64);

    __shared__ float wsum[BLOCK / 64];
    const int lane = t & 63;
    const int wid  = t >> 6;
    if (lane == 0) wsum[wid] = acc;
    __syncthreads();

    if (t == 0)
        partial[b] = (wsum[0] + wsum[1]) + (wsum[2] + wsum[3]);
}

// Reduce nblk partials -> single scalar. nblk = 2048 -> 8KB read.
__global__ __launch_bounds__(BLOCK)
void xing_reduce_kernel(const float* __restrict__ partial,
                        const int*   __restrict__ scale_p,
                        float*       __restrict__ out,
                        int nblk, int P)
{
    const int t = threadIdx.x;
    const float4* pf4 = reinterpret_cast<const float4*>(partial);
    const int nf4 = nblk / 4;   // 512

    float sum = 0.0f;
    for (int i = t; i < nf4; i += BLOCK) {
        float4 v = pf4[i];
        sum += (v.x + v.y) + (v.z + v.w);
    }

    #pragma unroll
    for (int off = 32; off > 0; off >>= 1)
        sum += __shfl_down(sum, off, 64);

    __shared__ float wsum[BLOCK / 64];
    const int lane = t & 63;
    const int wid  = t >> 6;
    if (lane == 0) wsum[wid] = sum;
    __syncthreads();

    if (t == 0) {
        const float total = (wsum[0] + wsum[1]) + (wsum[2] + wsum[3]);
        out[0] = total * (float)(*scale_p) / ((float)SEGN * (float)P);
    }
}

extern "C" void kernel_launch(void* const* d_in, const int* in_sizes, int n_in,
                              void* d_out, int out_size, void* d_ws, size_t ws_size,
                              hipStream_t stream)
{
    const float* x       = (const float*)d_in[0];
    const int*   scale_p = (const int*)d_in[1];
    float*       out     = (float*)d_out;
    float*       partial = (float*)d_ws;

    const int P    = in_sizes[0] / (N_PTS * 2);   // 16384 (element count)
    const int nblk = P / ROWS;                    // 2048

    xing_partial_kernel<<<nblk, BLOCK, 0, stream>>>(x, partial);
    xing_reduce_kernel<<<1, BLOCK, 0, stream>>>(partial, scale_p, out, nblk, P);
}